// Round 7
// baseline (1344.157 us; speedup 1.0000x reference)
//
#include <hip/hip_runtime.h>

#define NN 8192
#define CC 512
#define DKK 64

typedef float f32x4 __attribute__((ext_vector_type(4)));
typedef float f32x16 __attribute__((ext_vector_type(16)));
typedef _Float16 f16x8 __attribute__((ext_vector_type(8)));
typedef _Float16 f16x4 __attribute__((ext_vector_type(4)));

__device__ __forceinline__ f32x4 mfma16(f16x8 a, f16x8 b, f32x4 c) {
    return __builtin_amdgcn_mfma_f32_16x16x32_f16(a, b, c, 0, 0, 0);
}
__device__ __forceinline__ f32x16 mfma32(f16x8 a, f16x8 b, f32x16 c) {
    return __builtin_amdgcn_mfma_f32_32x32x16_f16(a, b, c, 0, 0, 0);
}
__device__ __forceinline__ f16x8 sclh8(f16x8 v, _Float16 h) {
    f16x8 r;
#pragma unroll
    for (int i = 0; i < 8; i++) r[i] = v[i] * h;
    return r;
}
__device__ __forceinline__ float exp2fast(float x) { return __builtin_exp2f(x); }

// ---- all weight transposes in one launch. grid 1280 x 256.
__global__ void wtrans_all_kernel(const float* __restrict__ Wq, const float* __restrict__ Wk,
                                  const float* __restrict__ Wv,
                                  _Float16* __restrict__ Wqt, _Float16* __restrict__ Wkt,
                                  _Float16* __restrict__ Wvf) {
    int idx = blockIdx.x * 256 + threadIdx.x;
    if (idx < 32768) {
        int n = idx >> 9, k = idx & 511;
        Wqt[idx] = (_Float16)Wq[k * 64 + n];
    } else if (idx < 65536) {
        int j = idx - 32768;
        int n = j >> 9, k = j & 511;
        Wkt[j] = (_Float16)Wk[k * 64 + n];
    } else {
        int j = idx - 65536;
        int k16 = j & 15, c = (j >> 4) & 511, ks = j >> 13;
        Wvf[j] = (_Float16)Wv[(size_t)(16 * ks + k16) * 512 + c];
    }
}

// ---- fused Q+K projection: Q[N][64] row-major f16 (PRE-SCALED by log2(e): flash
// softmax runs in the exp2 domain); K -> frag-major Kf[tile][ks][kv6][k16]
__global__ __launch_bounds__(256) void proj_qk2_kernel(
    const float* __restrict__ im1, const float* __restrict__ im2,
    const _Float16* __restrict__ Wqt, const _Float16* __restrict__ Wkt,
    _Float16* __restrict__ Q1, _Float16* __restrict__ Kf1,
    _Float16* __restrict__ Q2, _Float16* __restrict__ Kf2)
{
    const float* X = blockIdx.y ? im2 : im1;
    _Float16* Q = blockIdx.y ? Q2 : Q1;
    _Float16* Kf = blockIdx.y ? Kf2 : Kf1;

    __shared__ __align__(16) _Float16 Wlds[128 * 512];  // 128 KB

    const int tid = threadIdx.x;
    const int lane = tid & 63, wave = tid >> 6;
    const int n16 = lane & 15, quad = lane >> 4;

#pragma unroll
    for (int i = 0; i < 32; i++) {
        const int idx = tid + 256 * i;
        const int row = idx >> 6, ch = idx & 63;
        const _Float16* src = (row < 64) ? (Wqt + (size_t)row * 512 + ch * 8)
                                         : (Wkt + (size_t)(row - 64) * 512 + ch * 8);
        *(f16x8*)&Wlds[row * 512 + ((ch ^ (row & 7)) * 8)] = *(const f16x8*)src;
    }
    __syncthreads();

    const int arow = blockIdx.x * 64 + wave * 16 + n16;
    f32x4 acc[8];
#pragma unroll
    for (int i = 0; i < 8; i++) acc[i] = (f32x4){0.f, 0.f, 0.f, 0.f};

    const float* xbase = X + (size_t)arow * 512 + quad * 8;
    for (int kk = 0; kk < 16; kk++) {
        f32x4 xa = *(const f32x4*)(xbase + kk * 32);
        f32x4 xb = *(const f32x4*)(xbase + kk * 32 + 4);
        f16x8 afrag;
#pragma unroll
        for (int j = 0; j < 4; j++) { afrag[j] = (_Float16)xa[j]; afrag[4 + j] = (_Float16)xb[j]; }
#pragma unroll
        for (int t = 0; t < 8; t++) {
            const int row = t * 16 + n16;
            f16x8 bfr = *(const f16x8*)&Wlds[row * 512 + (((4 * kk + quad) ^ (row & 7)) * 8)];
            acc[t] = mfma16(afrag, bfr, acc[t]);
        }
    }
    const int rbase = blockIdx.x * 64 + wave * 16 + quad * 4;
#pragma unroll
    for (int t = 0; t < 4; t++)
#pragma unroll
        for (int r = 0; r < 4; r++) {
            Q[(size_t)(rbase + r) * 64 + t * 16 + n16] = (_Float16)(acc[t][r] * 1.44269504f);
            Kf[((size_t)(blockIdx.x * 4 + t) * 64 + (wave * 16 + quad * 4 + r)) * 16 + n16] =
                (_Float16)acc[4 + t][r];
        }
}

// ---- V projection -> LDS-matched layout Vf[tile][ks][k16hi][c][k8]
// (so flash staging is a LINEAR copy and the PV ds_read is lane-contiguous 16B,
//  conflict-free: addr = (ks*2+lhi)*8192B + c*16B)
__global__ __launch_bounds__(256) void proj_vt_kernel(
    const float* __restrict__ im1, const float* __restrict__ im2,
    const _Float16* __restrict__ Wvf,
    _Float16* __restrict__ Vf1, _Float16* __restrict__ Vf2)
{
    const float* X = blockIdx.y ? im2 : im1;
    _Float16* Vf = blockIdx.y ? Vf2 : Vf1;
    const int n0 = blockIdx.x * 32;
    const int tid = threadIdx.x;
    const int lane = tid & 63, wave = tid >> 6;
    const int l31 = lane & 31, lhi = lane >> 5;

    __shared__ __align__(16) _Float16 Xlds[32 * 512];

#pragma unroll
    for (int i = 0; i < 8; i++) {
        const int n = tid >> 3;
        const int chunk = (tid & 7) + 8 * i;
        const float* xp = X + (size_t)(n0 + n) * CC + chunk * 8;
        f32x4 x0 = *(const f32x4*)xp;
        f32x4 x1 = *(const f32x4*)(xp + 4);
        f16x8 d;
#pragma unroll
        for (int j = 0; j < 4; j++) { d[j] = (_Float16)x0[j]; d[4 + j] = (_Float16)x1[j]; }
        *(f16x8*)&Xlds[n * 512 + ((chunk ^ (n & 7)) * 8)] = d;
    }
    __syncthreads();

    f32x16 acc[4];
#pragma unroll
    for (int t = 0; t < 4; t++)
#pragma unroll
        for (int r = 0; r < 16; r++) acc[t][r] = 0.f;

    for (int ks = 0; ks < 32; ks++) {
        f16x8 xb = *(const f16x8*)&Xlds[l31 * 512 + (((2 * ks + lhi) ^ (l31 & 7)) * 8)];
#pragma unroll
        for (int ct = 0; ct < 4; ct++) {
            const _Float16* wp = Wvf + ((size_t)ks * 512 + 128 * wave + 32 * ct + l31) * 16 + 8 * lhi;
            acc[ct] = mfma32(*(const f16x8*)wp, xb, acc[ct]);
        }
    }
    const int tile = n0 >> 6;
    const int ksbase = (n0 & 32) >> 4;  // 0 or 2
#pragma unroll
    for (int ct = 0; ct < 4; ct++)
#pragma unroll
        for (int r = 0; r < 16; r++) {
            const int c = 128 * wave + 32 * ct + (r & 3) + 8 * (r >> 2) + 4 * lhi;
            const int ks = ksbase + (l31 >> 4);
            const int k16 = l31 & 15;
            Vf[(size_t)(tile * 4 + ks) * 8192 + (k16 >> 3) * 4096 + c * 8 + (k16 & 7)] =
                (_Float16)acc[ct][r];
        }
}

// ---- flash18: flash17 structure (V through LDS dbuf, 1-tile slots, q=64,
// 1024 thr/16 waves, grid 256, 1 blk/CU) with the three VALU/balance fixes:
// (1) SHARED-REF P scaling: QK writes P relative to max(mg_lag2, tilemax); all
//     waves track mg identically, so in the common (no-new-max) case
//     f0=f1=al=1 EXACTLY -> skip all merge exp2s, sclh8, acc rescale. Exact math.
// (2) QK waves = {0,5,10,15} (a=qi&1, b=qi>>1): SIMD-balanced under both i%4
//     and i>>2 wave->SIMD mappings (flash17's {0..3} could pile on one SIMD).
// (3) V LDS layout [ks][k16hi][c][k8] (Vf pre-swizzled): PV ds_read is
//     lane-contiguous 16B, conflict-free (was 8-way at 32B stride).
__global__ __launch_bounds__(1024, 4) void flash18_kernel(
    const _Float16* __restrict__ Q1, const _Float16* __restrict__ Kf1,
    const _Float16* __restrict__ Q2, const _Float16* __restrict__ Kf2,
    const _Float16* __restrict__ Vf1, const _Float16* __restrict__ Vf2,
    const float* __restrict__ im1, const float* __restrict__ im2,
    float* __restrict__ out)
{
    const int bid = blockIdx.x;
    const int img = bid & 1;
    const int qbase = (bid >> 1) * 64;
    const _Float16* Q = img ? Q1 : Q2;
    const _Float16* Kf = img ? Kf2 : Kf1;
    const _Float16* Vf = img ? Vf2 : Vf1;
    const float* res = img ? im2 : im1;
    float* o = out + (size_t)img * NN * CC;

    __shared__ __align__(16) _Float16 Vs[2][4 * 2 * 512 * 8];  // [buf][(ks*2+h)*4096+c*8+k8] 128 KB
    __shared__ __align__(16) _Float16 P[2][8][64][8];          // [buf][chunk][q][fine] 16 KB
    __shared__ float mPart[2][2][64];                          // [buf][a][q]
    __shared__ float mF[2][64], lF[2][64];

    const int tid = threadIdx.x;
    const int lane = tid & 63, w = tid >> 6;
    const int l31 = lane & 31, lhi = lane >> 5;
    const bool isqk = (w == 0) | (w == 5) | (w == 10) | (w == 15);
    const int qi = w / 5;              // 0..3 for the QK waves
    const int a = qi & 1, b = qi >> 1;

    // ---- PV state: wave owns cols 32w..32w+31 over 64 q (2 q-halves)
    f32x16 acc[2];
#pragma unroll
    for (int t = 0; t < 2; t++)
#pragma unroll
        for (int r = 0; r < 16; r++) acc[t][r] = 0.f;
    float mg_run[2] = {-3e38f, -3e38f};

    // ---- QK state (QK waves only): stream = kv-half a, q-half b
    f16x8 qf[4], kreg[4];
    float ma_run = -3e38f, l_run = 0.f;

    const _Float16* kb = Kf + (size_t)(32 * a + l31) * 16 + 8 * lhi;

    if (isqk) {
        const _Float16* qp = Q + (size_t)(qbase + 32 * b + l31) * DKK + 8 * lhi;
#pragma unroll
        for (int k = 0; k < 4; k++) qf[k] = *(const f16x8*)(qp + 16 * k);
#pragma unroll
        for (int k = 0; k < 4; k++) kreg[k] = *(const f16x8*)(kb + (size_t)k * 1024);
    }

    // staged V regs (wave share = 2048 elems of the 32768-elem tile, linear copy)
    f16x8 st0, st1, st2, st3;
    auto stage_issue = [&](int t) {
        const _Float16* src = Vf + (size_t)t * 32768 + w * 2048 + lane * 8;
        st0 = *(const f16x8*)(src);
        st1 = *(const f16x8*)(src + 512);
        st2 = *(const f16x8*)(src + 1024);
        st3 = *(const f16x8*)(src + 1536);
    };
    auto stage_write = [&](int t) {
        _Float16* dst = &Vs[t & 1][0] + w * 2048 + lane * 8;
        *(f16x8*)(dst) = st0;
        *(f16x8*)(dst + 512) = st1;
        *(f16x8*)(dst + 1024) = st2;
        *(f16x8*)(dst + 1536) = st3;
    };

    // QK for tile ss: consumes kreg, prefetches kreg(ss+1). SHARED-REF: reference
    // max = max(mg_run[b] (merged max as of 2 slots back, known deterministically),
    // own prev ref, tile max). mg_run[b] >= ma_run always (prev tile max was merged),
    // so the l-update factor is exact and monotone.
    auto do_qk = [&](int ss) {
        const int pbuf = ss & 1;
        f32x16 sA;
#pragma unroll
        for (int r = 0; r < 16; r++) sA[r] = 0.f;
#pragma unroll
        for (int k = 0; k < 4; k++) sA = mfma32(kreg[k], qf[k], sA);
        if (ss + 1 < 128) {
#pragma unroll
            for (int k = 0; k < 4; k++)
                kreg[k] = *(const f16x8*)(kb + (size_t)((ss + 1) * 4 + k) * 1024);
        }
        float mr[8];
#pragma unroll
        for (int i = 0; i < 8; i++) mr[i] = fmaxf(sA[i], sA[i + 8]);
#pragma unroll
        for (int i = 0; i < 4; i++) mr[i] = fmaxf(mr[i], mr[i + 4]);
        float mx = fmaxf(fmaxf(mr[0], mr[1]), fmaxf(mr[2], mr[3]));
        mx = fmaxf(mx, __shfl_xor(mx, 32));
        const float manew = fmaxf(fmaxf(mg_run[b], ma_run), mx);
        if (lane < 32) mPart[pbuf][a][32 * b + lane] = manew;
        float ls = 0.f;
#pragma unroll
        for (int r = 0; r < 16; r++) {
            float p = exp2fast(sA[r] - manew);
            ls += p;
            sA[r] = p;
        }
        ls += __shfl_xor(ls, 32);
        l_run = l_run * exp2fast(ma_run - manew) + ls;
        ma_run = manew;
        // kv_local = (r&3) + 8*(r>>2) + 4*lhi + 32*a -> chunk 4a+(r>>2)
#pragma unroll
        for (int gg = 0; gg < 4; gg++) {
            f16x4 p4;
#pragma unroll
            for (int u = 0; u < 4; u++) p4[u] = (_Float16)sA[gg * 4 + u];
            *(f16x4*)&P[pbuf][4 * a + gg][32 * b + l31][4 * lhi] = p4;
        }
    };

    // ---- prologue
    stage_issue(0);
    if (isqk) do_qk(0);
    stage_write(0);
    __syncthreads();

    for (int s = 0; s < 128; s++) {
        const int pbuf = s & 1;
        if (s < 127) {
            stage_issue(s + 1);           // V(s+1) global loads in flight
            if (isqk) do_qk(s + 1);       // writes P[(s+1)&1], mPart[(s+1)&1]
        }

        // ---- merge (shared-ref fast path: no exp2, no rescale when no new max)
        float lal[2], lf0[2], lf1[2];
        bool fastall = true;
#pragma unroll
        for (int qh = 0; qh < 2; qh++) {
            const int q = 32 * qh + l31;
            const float m0 = mPart[pbuf][0][q];
            const float m1 = mPart[pbuf][1][q];
            const float mgo = mg_run[qh];
            const float mgn = fmaxf(mgo, fmaxf(m0, m1));
            fastall &= (m0 == mgn) & (m1 == mgn) & (mgo == mgn);
            mg_run[qh] = mgn;
            lal[qh] = mgo - mgn;
            lf0[qh] = m0 - mgn;
            lf1[qh] = m1 - mgn;
        }
        const bool nos = __all(fastall);
        const _Float16* vbufp = &Vs[pbuf][0];

        if (nos) {
#pragma unroll
            for (int ks = 0; ks < 4; ks++) {
                f16x8 va = *(const f16x8*)(vbufp + (ks * 2 + lhi) * 4096 + (32 * w + l31) * 8);
                f16x8 pb0 = *(const f16x8*)&P[pbuf][2 * ks + lhi][l31][0];
                f16x8 pb1 = *(const f16x8*)&P[pbuf][2 * ks + lhi][32 + l31][0];
                acc[0] = mfma32(va, pb0, acc[0]);
                acc[1] = mfma32(va, pb1, acc[1]);
            }
        } else {
            float f[2][2], al[2];
#pragma unroll
            for (int qh = 0; qh < 2; qh++) {
                al[qh] = exp2fast(lal[qh]);
                f[qh][0] = exp2fast(lf0[qh]);
                f[qh][1] = exp2fast(lf1[qh]);
            }
#pragma unroll
            for (int qh = 0; qh < 2; qh++)
#pragma unroll
                for (int r = 0; r < 16; r++) acc[qh][r] *= al[qh];
#pragma unroll
            for (int ks = 0; ks < 4; ks++) {
                f16x8 va = *(const f16x8*)(vbufp + (ks * 2 + lhi) * 4096 + (32 * w + l31) * 8);
                f16x8 pb0 = *(const f16x8*)&P[pbuf][2 * ks + lhi][l31][0];
                f16x8 pb1 = *(const f16x8*)&P[pbuf][2 * ks + lhi][32 + l31][0];
                pb0 = sclh8(pb0, (_Float16)f[0][ks >> 1]);
                pb1 = sclh8(pb1, (_Float16)f[1][ks >> 1]);
                acc[0] = mfma32(va, pb0, acc[0]);
                acc[1] = mfma32(va, pb1, acc[1]);
            }
        }

        if (s < 127) stage_write(s + 1);  // V(s+1) -> other buffer
        __syncthreads();                  // P/mPart(s+1) + V(s+1) visible; slot-s reads done
    }

    // ---- epilogue: 2-stream denominator; direct store with residual
    if (isqk && lane < 32) {
        mF[a][32 * b + lane] = ma_run;
        lF[a][32 * b + lane] = l_run;
    }
    __syncthreads();

    float fac[2];
#pragma unroll
    for (int qh = 0; qh < 2; qh++) {
        const int q = 32 * qh + l31;
        const float M = mg_run[qh];  // final merged max (>= both stream refs)
        float den = 0.f;
#pragma unroll
        for (int a2 = 0; a2 < 2; a2++)
            den += lF[a2][q] * exp2fast(mF[a2][q] - M);
        fac[qh] = 1.f / den;
    }

#pragma unroll
    for (int qh = 0; qh < 2; qh++)
#pragma unroll
        for (int rg = 0; rg < 4; rg++) {
            const int c = 32 * w + 8 * rg + 4 * lhi;
            const size_t off = (size_t)(qbase + 32 * qh + l31) * CC + c;
            f32x4 v;
#pragma unroll
            for (int u = 0; u < 4; u++) v[u] = acc[qh][4 * rg + u] * fac[qh];
            f32x4 r4 = *(const f32x4*)(res + off);
            *(f32x4*)(o + off) = v + r4;
        }
}

extern "C" void kernel_launch(void* const* d_in, const int* in_sizes, int n_in,
                              void* d_out, int out_size, void* d_ws, size_t ws_size,
                              hipStream_t stream) {
    const float* im1 = (const float*)d_in[0];
    const float* im2 = (const float*)d_in[1];
    const float* Wq  = (const float*)d_in[2];
    const float* Wk  = (const float*)d_in[3];
    const float* Wv  = (const float*)d_in[4];
    float* out = (float*)d_out;

    _Float16* w = (_Float16*)d_ws;
    _Float16* Wqt = w;                      // 64*512
    _Float16* Wkt = Wqt + 64 * 512;
    _Float16* Wvf = Wkt + 64 * 512;         // 512*512 frag-major
    _Float16* Q1  = Wvf + 512 * 512;        // 8192*64 each
    _Float16* Kf1 = Q1 + NN * DKK;
    _Float16* Q2  = Kf1 + NN * DKK;
    _Float16* Kf2 = Q2 + NN * DKK;
    _Float16* Vf1 = Kf2 + NN * DKK;         // LDS-matched [128][4][2][512][8] each
    _Float16* Vf2 = Vf1 + (size_t)CC * NN;

    wtrans_all_kernel<<<1280, 256, 0, stream>>>(Wq, Wk, Wv, Wqt, Wkt, Wvf);
    proj_qk2_kernel<<<dim3(128, 2), 256, 0, stream>>>(im1, im2, Wqt, Wkt, Q1, Kf1, Q2, Kf2);
    proj_vt_kernel<<<dim3(256, 2), 256, 0, stream>>>(im1, im2, Wvf, Vf1, Vf2);
    flash18_kernel<<<256, 1024, 0, stream>>>(Q1, Kf1, Q2, Kf2, Vf1, Vf2, im1, im2, out);
}

// Round 8
// 1057.176 us; speedup vs baseline: 1.2715x; 1.2715x over previous
//
#include <hip/hip_runtime.h>

#define NN 8192
#define CC 512
#define DKK 64

typedef float f32x4 __attribute__((ext_vector_type(4)));
typedef float f32x16 __attribute__((ext_vector_type(16)));
typedef _Float16 f16x8 __attribute__((ext_vector_type(8)));
typedef _Float16 f16x4 __attribute__((ext_vector_type(4)));

__device__ __forceinline__ f32x4 mfma16(f16x8 a, f16x8 b, f32x4 c) {
    return __builtin_amdgcn_mfma_f32_16x16x32_f16(a, b, c, 0, 0, 0);
}
__device__ __forceinline__ f32x16 mfma32(f16x8 a, f16x8 b, f32x16 c) {
    return __builtin_amdgcn_mfma_f32_32x32x16_f16(a, b, c, 0, 0, 0);
}
__device__ __forceinline__ f16x8 sclh8(f16x8 v, _Float16 h) {
    f16x8 r;
#pragma unroll
    for (int i = 0; i < 8; i++) r[i] = v[i] * h;
    return r;
}
__device__ __forceinline__ float exp2fast(float x) { return __builtin_exp2f(x); }

// ---- all weight transposes in one launch. grid 1280 x 256.
__global__ void wtrans_all_kernel(const float* __restrict__ Wq, const float* __restrict__ Wk,
                                  const float* __restrict__ Wv,
                                  _Float16* __restrict__ Wqt, _Float16* __restrict__ Wkt,
                                  _Float16* __restrict__ Wvf) {
    int idx = blockIdx.x * 256 + threadIdx.x;
    if (idx < 32768) {
        int n = idx >> 9, k = idx & 511;
        Wqt[idx] = (_Float16)Wq[k * 64 + n];
    } else if (idx < 65536) {
        int j = idx - 32768;
        int n = j >> 9, k = j & 511;
        Wkt[j] = (_Float16)Wk[k * 64 + n];
    } else {
        int j = idx - 65536;
        int k16 = j & 15, c = (j >> 4) & 511, ks = j >> 13;
        Wvf[j] = (_Float16)Wv[(size_t)(16 * ks + k16) * 512 + c];
    }
}

// ---- fused Q+K projection: Q[N][64] row-major f16 (PRE-SCALED by log2(e): flash
// softmax runs in the exp2 domain); K -> frag-major Kf[tile][ks][kv6][k16]
__global__ __launch_bounds__(256) void proj_qk2_kernel(
    const float* __restrict__ im1, const float* __restrict__ im2,
    const _Float16* __restrict__ Wqt, const _Float16* __restrict__ Wkt,
    _Float16* __restrict__ Q1, _Float16* __restrict__ Kf1,
    _Float16* __restrict__ Q2, _Float16* __restrict__ Kf2)
{
    const float* X = blockIdx.y ? im2 : im1;
    _Float16* Q = blockIdx.y ? Q2 : Q1;
    _Float16* Kf = blockIdx.y ? Kf2 : Kf1;

    __shared__ __align__(16) _Float16 Wlds[128 * 512];  // 128 KB

    const int tid = threadIdx.x;
    const int lane = tid & 63, wave = tid >> 6;
    const int n16 = lane & 15, quad = lane >> 4;

#pragma unroll
    for (int i = 0; i < 32; i++) {
        const int idx = tid + 256 * i;
        const int row = idx >> 6, ch = idx & 63;
        const _Float16* src = (row < 64) ? (Wqt + (size_t)row * 512 + ch * 8)
                                         : (Wkt + (size_t)(row - 64) * 512 + ch * 8);
        *(f16x8*)&Wlds[row * 512 + ((ch ^ (row & 7)) * 8)] = *(const f16x8*)src;
    }
    __syncthreads();

    const int arow = blockIdx.x * 64 + wave * 16 + n16;
    f32x4 acc[8];
#pragma unroll
    for (int i = 0; i < 8; i++) acc[i] = (f32x4){0.f, 0.f, 0.f, 0.f};

    const float* xbase = X + (size_t)arow * 512 + quad * 8;
    for (int kk = 0; kk < 16; kk++) {
        f32x4 xa = *(const f32x4*)(xbase + kk * 32);
        f32x4 xb = *(const f32x4*)(xbase + kk * 32 + 4);
        f16x8 afrag;
#pragma unroll
        for (int j = 0; j < 4; j++) { afrag[j] = (_Float16)xa[j]; afrag[4 + j] = (_Float16)xb[j]; }
#pragma unroll
        for (int t = 0; t < 8; t++) {
            const int row = t * 16 + n16;
            f16x8 bfr = *(const f16x8*)&Wlds[row * 512 + (((4 * kk + quad) ^ (row & 7)) * 8)];
            acc[t] = mfma16(afrag, bfr, acc[t]);
        }
    }
    const int rbase = blockIdx.x * 64 + wave * 16 + quad * 4;
#pragma unroll
    for (int t = 0; t < 4; t++)
#pragma unroll
        for (int r = 0; r < 4; r++) {
            Q[(size_t)(rbase + r) * 64 + t * 16 + n16] = (_Float16)(acc[t][r] * 1.44269504f);
            Kf[((size_t)(blockIdx.x * 4 + t) * 64 + (wave * 16 + quad * 4 + r)) * 16 + n16] =
                (_Float16)acc[4 + t][r];
        }
}

// ---- V projection -> LDS-matched layout Vf[tile][ks][k16hi][c][k8]
// (so flash staging is a LINEAR copy and the PV ds_read is lane-contiguous 16B,
//  conflict-free: addr = (ks*2+lhi)*8192B + c*16B)
__global__ __launch_bounds__(256) void proj_vt_kernel(
    const float* __restrict__ im1, const float* __restrict__ im2,
    const _Float16* __restrict__ Wvf,
    _Float16* __restrict__ Vf1, _Float16* __restrict__ Vf2)
{
    const float* X = blockIdx.y ? im2 : im1;
    _Float16* Vf = blockIdx.y ? Vf2 : Vf1;
    const int n0 = blockIdx.x * 32;
    const int tid = threadIdx.x;
    const int lane = tid & 63, wave = tid >> 6;
    const int l31 = lane & 31, lhi = lane >> 5;

    __shared__ __align__(16) _Float16 Xlds[32 * 512];

#pragma unroll
    for (int i = 0; i < 8; i++) {
        const int n = tid >> 3;
        const int chunk = (tid & 7) + 8 * i;
        const float* xp = X + (size_t)(n0 + n) * CC + chunk * 8;
        f32x4 x0 = *(const f32x4*)xp;
        f32x4 x1 = *(const f32x4*)(xp + 4);
        f16x8 d;
#pragma unroll
        for (int j = 0; j < 4; j++) { d[j] = (_Float16)x0[j]; d[4 + j] = (_Float16)x1[j]; }
        *(f16x8*)&Xlds[n * 512 + ((chunk ^ (n & 7)) * 8)] = d;
    }
    __syncthreads();

    f32x16 acc[4];
#pragma unroll
    for (int t = 0; t < 4; t++)
#pragma unroll
        for (int r = 0; r < 16; r++) acc[t][r] = 0.f;

    for (int ks = 0; ks < 32; ks++) {
        f16x8 xb = *(const f16x8*)&Xlds[l31 * 512 + (((2 * ks + lhi) ^ (l31 & 7)) * 8)];
#pragma unroll
        for (int ct = 0; ct < 4; ct++) {
            const _Float16* wp = Wvf + ((size_t)ks * 512 + 128 * wave + 32 * ct + l31) * 16 + 8 * lhi;
            acc[ct] = mfma32(*(const f16x8*)wp, xb, acc[ct]);
        }
    }
    const int tile = n0 >> 6;
    const int ksbase = (n0 & 32) >> 4;  // 0 or 2
#pragma unroll
    for (int ct = 0; ct < 4; ct++)
#pragma unroll
        for (int r = 0; r < 16; r++) {
            const int c = 128 * wave + 32 * ct + (r & 3) + 8 * (r >> 2) + 4 * lhi;
            const int ks = ksbase + (l31 >> 4);
            const int k16 = l31 & 15;
            Vf[(size_t)(tile * 4 + ks) * 8192 + (k16 >> 3) * 4096 + c * 8 + (k16 & 7)] =
                (_Float16)acc[ct][r];
        }
}

// ---- flash19: flash18 with the scratch-spill fix. flash18's counters proved
// the Vf swizzle (conflicts 10.5M->2.1M) and the shared-ref math (passed), but
// `mg_run[b]` (runtime-indexed private array, rule #20) forced mg_run + the
// staged V regs into scratch -> 4.4 GB HBM writes. Fix: branchless STATIC select
// (b ? mg_run[1] : mg_run[0]) -> v_cndmask on named values, no scratch.
// Structure unchanged: V through LDS dbuf, 1-tile slots, q=64, 1024 thr/16
// waves, grid 256, 1 blk/CU, QK waves {0,5,10,15}, shared-ref fast path
// (f==1 exactly on max-plateau -> skip sclh8/rescale/exp2).
__global__ __launch_bounds__(1024, 4) void flash19_kernel(
    const _Float16* __restrict__ Q1, const _Float16* __restrict__ Kf1,
    const _Float16* __restrict__ Q2, const _Float16* __restrict__ Kf2,
    const _Float16* __restrict__ Vf1, const _Float16* __restrict__ Vf2,
    const float* __restrict__ im1, const float* __restrict__ im2,
    float* __restrict__ out)
{
    const int bid = blockIdx.x;
    const int img = bid & 1;
    const int qbase = (bid >> 1) * 64;
    const _Float16* Q = img ? Q1 : Q2;
    const _Float16* Kf = img ? Kf2 : Kf1;
    const _Float16* Vf = img ? Vf2 : Vf1;
    const float* res = img ? im2 : im1;
    float* o = out + (size_t)img * NN * CC;

    __shared__ __align__(16) _Float16 Vs[2][4 * 2 * 512 * 8];  // [buf][(ks*2+h)*4096+c*8+k8] 128 KB
    __shared__ __align__(16) _Float16 P[2][8][64][8];          // [buf][chunk][q][fine] 16 KB
    __shared__ float mPart[2][2][64];                          // [buf][a][q]
    __shared__ float mF[2][64], lF[2][64];

    const int tid = threadIdx.x;
    const int lane = tid & 63, w = tid >> 6;
    const int l31 = lane & 31, lhi = lane >> 5;
    const bool isqk = (w == 0) | (w == 5) | (w == 10) | (w == 15);
    const int qi = w / 5;              // 0..3 for the QK waves
    const int a = qi & 1, b = qi >> 1;

    // ---- PV state: wave owns cols 32w..32w+31 over 64 q (2 q-halves)
    f32x16 acc[2];
#pragma unroll
    for (int t = 0; t < 2; t++)
#pragma unroll
        for (int r = 0; r < 16; r++) acc[t][r] = 0.f;
    float mg_run0 = -3e38f, mg_run1 = -3e38f;  // named (NOT an array): no runtime indexing

    // ---- QK state (QK waves only): stream = kv-half a, q-half b
    f16x8 qf[4], kreg[4];
    float ma_run = -3e38f, l_run = 0.f;

    const _Float16* kb = Kf + (size_t)(32 * a + l31) * 16 + 8 * lhi;

    if (isqk) {
        const _Float16* qp = Q + (size_t)(qbase + 32 * b + l31) * DKK + 8 * lhi;
#pragma unroll
        for (int k = 0; k < 4; k++) qf[k] = *(const f16x8*)(qp + 16 * k);
#pragma unroll
        for (int k = 0; k < 4; k++) kreg[k] = *(const f16x8*)(kb + (size_t)k * 1024);
    }

    // staged V regs (wave share = 2048 elems of the 32768-elem tile, linear copy)
    f16x8 st0, st1, st2, st3;
    auto stage_issue = [&](int t) {
        const _Float16* src = Vf + (size_t)t * 32768 + w * 2048 + lane * 8;
        st0 = *(const f16x8*)(src);
        st1 = *(const f16x8*)(src + 512);
        st2 = *(const f16x8*)(src + 1024);
        st3 = *(const f16x8*)(src + 1536);
    };
    auto stage_write = [&](int t) {
        _Float16* dst = &Vs[t & 1][0] + w * 2048 + lane * 8;
        *(f16x8*)(dst) = st0;
        *(f16x8*)(dst + 512) = st1;
        *(f16x8*)(dst + 1024) = st2;
        *(f16x8*)(dst + 1536) = st3;
    };

    // QK for tile ss: consumes kreg, prefetches kreg(ss+1). SHARED-REF: reference
    // max = max(merged max as of 2 slots back (branchless static select on b),
    // own prev ref, tile max). Merged max >= ma_run always, so the l-update
    // factor is exact and monotone.
    auto do_qk = [&](int ss) {
        const int pbuf = ss & 1;
        f32x16 sA;
#pragma unroll
        for (int r = 0; r < 16; r++) sA[r] = 0.f;
#pragma unroll
        for (int k = 0; k < 4; k++) sA = mfma32(kreg[k], qf[k], sA);
        if (ss + 1 < 128) {
#pragma unroll
            for (int k = 0; k < 4; k++)
                kreg[k] = *(const f16x8*)(kb + (size_t)((ss + 1) * 4 + k) * 1024);
        }
        float mr[8];
#pragma unroll
        for (int i = 0; i < 8; i++) mr[i] = fmaxf(sA[i], sA[i + 8]);
#pragma unroll
        for (int i = 0; i < 4; i++) mr[i] = fmaxf(mr[i], mr[i + 4]);
        float mx = fmaxf(fmaxf(mr[0], mr[1]), fmaxf(mr[2], mr[3]));
        mx = fmaxf(mx, __shfl_xor(mx, 32));
        const float mgb = b ? mg_run1 : mg_run0;  // static select, no scratch
        const float manew = fmaxf(fmaxf(mgb, ma_run), mx);
        if (lane < 32) mPart[pbuf][a][32 * b + lane] = manew;
        float ls = 0.f;
#pragma unroll
        for (int r = 0; r < 16; r++) {
            float p = exp2fast(sA[r] - manew);
            ls += p;
            sA[r] = p;
        }
        ls += __shfl_xor(ls, 32);
        l_run = l_run * exp2fast(ma_run - manew) + ls;
        ma_run = manew;
        // kv_local = (r&3) + 8*(r>>2) + 4*lhi + 32*a -> chunk 4a+(r>>2)
#pragma unroll
        for (int gg = 0; gg < 4; gg++) {
            f16x4 p4;
#pragma unroll
            for (int u = 0; u < 4; u++) p4[u] = (_Float16)sA[gg * 4 + u];
            *(f16x4*)&P[pbuf][4 * a + gg][32 * b + l31][4 * lhi] = p4;
        }
    };

    // ---- prologue
    stage_issue(0);
    if (isqk) do_qk(0);
    stage_write(0);
    __syncthreads();

    for (int s = 0; s < 128; s++) {
        const int pbuf = s & 1;
        if (s < 127) {
            stage_issue(s + 1);           // V(s+1) global loads in flight
            if (isqk) do_qk(s + 1);       // writes P[(s+1)&1], mPart[(s+1)&1]
        }

        // ---- merge (shared-ref fast path: no exp2, no rescale when no new max)
        float lal0, lal1, lf00, lf01, lf10, lf11;
        bool fastall;
        {
            const float m00 = mPart[pbuf][0][l31];
            const float m10 = mPart[pbuf][1][l31];
            const float mgn0 = fmaxf(mg_run0, fmaxf(m00, m10));
            const float m01 = mPart[pbuf][0][32 + l31];
            const float m11 = mPart[pbuf][1][32 + l31];
            const float mgn1 = fmaxf(mg_run1, fmaxf(m01, m11));
            fastall = (m00 == mgn0) & (m10 == mgn0) & (mg_run0 == mgn0) &
                      (m01 == mgn1) & (m11 == mgn1) & (mg_run1 == mgn1);
            lal0 = mg_run0 - mgn0;  lal1 = mg_run1 - mgn1;
            lf00 = m00 - mgn0;      lf01 = m01 - mgn1;
            lf10 = m10 - mgn0;      lf11 = m11 - mgn1;
            mg_run0 = mgn0;         mg_run1 = mgn1;
        }
        const bool nos = __all(fastall);
        const _Float16* vbufp = &Vs[pbuf][0];

        if (nos) {
#pragma unroll
            for (int ks = 0; ks < 4; ks++) {
                f16x8 va = *(const f16x8*)(vbufp + (ks * 2 + lhi) * 4096 + (32 * w + l31) * 8);
                f16x8 pb0 = *(const f16x8*)&P[pbuf][2 * ks + lhi][l31][0];
                f16x8 pb1 = *(const f16x8*)&P[pbuf][2 * ks + lhi][32 + l31][0];
                acc[0] = mfma32(va, pb0, acc[0]);
                acc[1] = mfma32(va, pb1, acc[1]);
            }
        } else {
            const float al0 = exp2fast(lal0), al1 = exp2fast(lal1);
            const float f00 = exp2fast(lf00), f01 = exp2fast(lf01);
            const float f10 = exp2fast(lf10), f11 = exp2fast(lf11);
#pragma unroll
            for (int r = 0; r < 16; r++) { acc[0][r] *= al0; acc[1][r] *= al1; }
#pragma unroll
            for (int ks = 0; ks < 4; ks++) {
                f16x8 va = *(const f16x8*)(vbufp + (ks * 2 + lhi) * 4096 + (32 * w + l31) * 8);
                f16x8 pb0 = *(const f16x8*)&P[pbuf][2 * ks + lhi][l31][0];
                f16x8 pb1 = *(const f16x8*)&P[pbuf][2 * ks + lhi][32 + l31][0];
                pb0 = sclh8(pb0, (_Float16)(ks < 2 ? f00 : f10));
                pb1 = sclh8(pb1, (_Float16)(ks < 2 ? f01 : f11));
                acc[0] = mfma32(va, pb0, acc[0]);
                acc[1] = mfma32(va, pb1, acc[1]);
            }
        }

        if (s < 127) stage_write(s + 1);  // V(s+1) -> other buffer
        __syncthreads();                  // P/mPart(s+1) + V(s+1) visible; slot-s reads done
    }

    // ---- epilogue: 2-stream denominator; direct store with residual
    if (isqk && lane < 32) {
        mF[a][32 * b + lane] = ma_run;
        lF[a][32 * b + lane] = l_run;
    }
    __syncthreads();

    float fac0, fac1;
    {
        const float M0 = mg_run0;  // final merged max (>= both stream refs)
        fac0 = 1.f / (lF[0][l31] * exp2fast(mF[0][l31] - M0) +
                      lF[1][l31] * exp2fast(mF[1][l31] - M0));
        const float M1 = mg_run1;
        fac1 = 1.f / (lF[0][32 + l31] * exp2fast(mF[0][32 + l31] - M1) +
                      lF[1][32 + l31] * exp2fast(mF[1][32 + l31] - M1));
    }

#pragma unroll
    for (int rg = 0; rg < 4; rg++) {
        const int c = 32 * w + 8 * rg + 4 * lhi;
        const size_t off0 = (size_t)(qbase + l31) * CC + c;
        const size_t off1 = (size_t)(qbase + 32 + l31) * CC + c;
        f32x4 v0, v1;
#pragma unroll
        for (int u = 0; u < 4; u++) { v0[u] = acc[0][4 * rg + u] * fac0; v1[u] = acc[1][4 * rg + u] * fac1; }
        f32x4 r0 = *(const f32x4*)(res + off0);
        f32x4 r1 = *(const f32x4*)(res + off1);
        *(f32x4*)(o + off0) = v0 + r0;
        *(f32x4*)(o + off1) = v1 + r1;
    }
}

extern "C" void kernel_launch(void* const* d_in, const int* in_sizes, int n_in,
                              void* d_out, int out_size, void* d_ws, size_t ws_size,
                              hipStream_t stream) {
    const float* im1 = (const float*)d_in[0];
    const float* im2 = (const float*)d_in[1];
    const float* Wq  = (const float*)d_in[2];
    const float* Wk  = (const float*)d_in[3];
    const float* Wv  = (const float*)d_in[4];
    float* out = (float*)d_out;

    _Float16* w = (_Float16*)d_ws;
    _Float16* Wqt = w;                      // 64*512
    _Float16* Wkt = Wqt + 64 * 512;
    _Float16* Wvf = Wkt + 64 * 512;         // 512*512 frag-major
    _Float16* Q1  = Wvf + 512 * 512;        // 8192*64 each
    _Float16* Kf1 = Q1 + NN * DKK;
    _Float16* Q2  = Kf1 + NN * DKK;
    _Float16* Kf2 = Q2 + NN * DKK;
    _Float16* Vf1 = Kf2 + NN * DKK;         // LDS-matched [128][4][2][512][8] each
    _Float16* Vf2 = Vf1 + (size_t)CC * NN;

    wtrans_all_kernel<<<1280, 256, 0, stream>>>(Wq, Wk, Wv, Wqt, Wkt, Wvf);
    proj_qk2_kernel<<<dim3(128, 2), 256, 0, stream>>>(im1, im2, Wqt, Wkt, Q1, Kf1, Q2, Kf2);
    proj_vt_kernel<<<dim3(256, 2), 256, 0, stream>>>(im1, im2, Wvf, Vf1, Vf2);
    flash19_kernel<<<256, 1024, 0, stream>>>(Q1, Kf1, Q2, Kf2, Vf1, Vf2, im1, im2, out);
}

// Round 9
// 626.283 us; speedup vs baseline: 2.1462x; 1.6880x over previous
//
#include <hip/hip_runtime.h>

#define NN 8192
#define CC 512
#define DKK 64

typedef float f32x4 __attribute__((ext_vector_type(4)));
typedef float f32x16 __attribute__((ext_vector_type(16)));
typedef _Float16 f16x8 __attribute__((ext_vector_type(8)));
typedef _Float16 f16x4 __attribute__((ext_vector_type(4)));

__device__ __forceinline__ f32x4 mfma16(f16x8 a, f16x8 b, f32x4 c) {
    return __builtin_amdgcn_mfma_f32_16x16x32_f16(a, b, c, 0, 0, 0);
}
__device__ __forceinline__ f32x16 mfma32(f16x8 a, f16x8 b, f32x16 c) {
    return __builtin_amdgcn_mfma_f32_32x32x16_f16(a, b, c, 0, 0, 0);
}
__device__ __forceinline__ f16x8 sclh8(f16x8 v, _Float16 h) {
    f16x8 r;
#pragma unroll
    for (int i = 0; i < 8; i++) r[i] = v[i] * h;
    return r;
}
__device__ __forceinline__ float exp2fast(float x) { return __builtin_exp2f(x); }

// async global->LDS, 16B per lane: per-lane global src, wave-uniform LDS base
// (dest = firstlane(l) + lane*16). Our staging is a linear copy, so legal.
__device__ __forceinline__ void async_cp16(const _Float16* g, _Float16* l) {
    __builtin_amdgcn_global_load_lds(
        (const __attribute__((address_space(1))) void*)g,
        (__attribute__((address_space(3))) void*)l, 16, 0, 0);
}

// ---- all weight transposes in one launch. grid 1280 x 256.
__global__ void wtrans_all_kernel(const float* __restrict__ Wq, const float* __restrict__ Wk,
                                  const float* __restrict__ Wv,
                                  _Float16* __restrict__ Wqt, _Float16* __restrict__ Wkt,
                                  _Float16* __restrict__ Wvf) {
    int idx = blockIdx.x * 256 + threadIdx.x;
    if (idx < 32768) {
        int n = idx >> 9, k = idx & 511;
        Wqt[idx] = (_Float16)Wq[k * 64 + n];
    } else if (idx < 65536) {
        int j = idx - 32768;
        int n = j >> 9, k = j & 511;
        Wkt[j] = (_Float16)Wk[k * 64 + n];
    } else {
        int j = idx - 65536;
        int k16 = j & 15, c = (j >> 4) & 511, ks = j >> 13;
        Wvf[j] = (_Float16)Wv[(size_t)(16 * ks + k16) * 512 + c];
    }
}

// ---- fused Q+K projection: Q[N][64] row-major f16 (PRE-SCALED by log2(e): flash
// softmax runs in the exp2 domain); K -> frag-major Kf[tile][ks][kv6][k16]
__global__ __launch_bounds__(256) void proj_qk2_kernel(
    const float* __restrict__ im1, const float* __restrict__ im2,
    const _Float16* __restrict__ Wqt, const _Float16* __restrict__ Wkt,
    _Float16* __restrict__ Q1, _Float16* __restrict__ Kf1,
    _Float16* __restrict__ Q2, _Float16* __restrict__ Kf2)
{
    const float* X = blockIdx.y ? im2 : im1;
    _Float16* Q = blockIdx.y ? Q2 : Q1;
    _Float16* Kf = blockIdx.y ? Kf2 : Kf1;

    __shared__ __align__(16) _Float16 Wlds[128 * 512];  // 128 KB

    const int tid = threadIdx.x;
    const int lane = tid & 63, wave = tid >> 6;
    const int n16 = lane & 15, quad = lane >> 4;

#pragma unroll
    for (int i = 0; i < 32; i++) {
        const int idx = tid + 256 * i;
        const int row = idx >> 6, ch = idx & 63;
        const _Float16* src = (row < 64) ? (Wqt + (size_t)row * 512 + ch * 8)
                                         : (Wkt + (size_t)(row - 64) * 512 + ch * 8);
        *(f16x8*)&Wlds[row * 512 + ((ch ^ (row & 7)) * 8)] = *(const f16x8*)src;
    }
    __syncthreads();

    const int arow = blockIdx.x * 64 + wave * 16 + n16;
    f32x4 acc[8];
#pragma unroll
    for (int i = 0; i < 8; i++) acc[i] = (f32x4){0.f, 0.f, 0.f, 0.f};

    const float* xbase = X + (size_t)arow * 512 + quad * 8;
    for (int kk = 0; kk < 16; kk++) {
        f32x4 xa = *(const f32x4*)(xbase + kk * 32);
        f32x4 xb = *(const f32x4*)(xbase + kk * 32 + 4);
        f16x8 afrag;
#pragma unroll
        for (int j = 0; j < 4; j++) { afrag[j] = (_Float16)xa[j]; afrag[4 + j] = (_Float16)xb[j]; }
#pragma unroll
        for (int t = 0; t < 8; t++) {
            const int row = t * 16 + n16;
            f16x8 bfr = *(const f16x8*)&Wlds[row * 512 + (((4 * kk + quad) ^ (row & 7)) * 8)];
            acc[t] = mfma16(afrag, bfr, acc[t]);
        }
    }
    const int rbase = blockIdx.x * 64 + wave * 16 + quad * 4;
#pragma unroll
    for (int t = 0; t < 4; t++)
#pragma unroll
        for (int r = 0; r < 4; r++) {
            Q[(size_t)(rbase + r) * 64 + t * 16 + n16] = (_Float16)(acc[t][r] * 1.44269504f);
            Kf[((size_t)(blockIdx.x * 4 + t) * 64 + (wave * 16 + quad * 4 + r)) * 16 + n16] =
                (_Float16)acc[4 + t][r];
        }
}

// ---- V projection -> LDS-matched layout Vf[tile][ks][k16hi][c][k8]
// (flash staging is a LINEAR copy; PV ds_read is lane-contiguous 16B, conflict-free)
__global__ __launch_bounds__(256) void proj_vt_kernel(
    const float* __restrict__ im1, const float* __restrict__ im2,
    const _Float16* __restrict__ Wvf,
    _Float16* __restrict__ Vf1, _Float16* __restrict__ Vf2)
{
    const float* X = blockIdx.y ? im2 : im1;
    _Float16* Vf = blockIdx.y ? Vf2 : Vf1;
    const int n0 = blockIdx.x * 32;
    const int tid = threadIdx.x;
    const int lane = tid & 63, wave = tid >> 6;
    const int l31 = lane & 31, lhi = lane >> 5;

    __shared__ __align__(16) _Float16 Xlds[32 * 512];

#pragma unroll
    for (int i = 0; i < 8; i++) {
        const int n = tid >> 3;
        const int chunk = (tid & 7) + 8 * i;
        const float* xp = X + (size_t)(n0 + n) * CC + chunk * 8;
        f32x4 x0 = *(const f32x4*)xp;
        f32x4 x1 = *(const f32x4*)(xp + 4);
        f16x8 d;
#pragma unroll
        for (int j = 0; j < 4; j++) { d[j] = (_Float16)x0[j]; d[4 + j] = (_Float16)x1[j]; }
        *(f16x8*)&Xlds[n * 512 + ((chunk ^ (n & 7)) * 8)] = d;
    }
    __syncthreads();

    f32x16 acc[4];
#pragma unroll
    for (int t = 0; t < 4; t++)
#pragma unroll
        for (int r = 0; r < 16; r++) acc[t][r] = 0.f;

    for (int ks = 0; ks < 32; ks++) {
        f16x8 xb = *(const f16x8*)&Xlds[l31 * 512 + (((2 * ks + lhi) ^ (l31 & 7)) * 8)];
#pragma unroll
        for (int ct = 0; ct < 4; ct++) {
            const _Float16* wp = Wvf + ((size_t)ks * 512 + 128 * wave + 32 * ct + l31) * 16 + 8 * lhi;
            acc[ct] = mfma32(*(const f16x8*)wp, xb, acc[ct]);
        }
    }
    const int tile = n0 >> 6;
    const int ksbase = (n0 & 32) >> 4;  // 0 or 2
#pragma unroll
    for (int ct = 0; ct < 4; ct++)
#pragma unroll
        for (int r = 0; r < 16; r++) {
            const int c = 128 * wave + 32 * ct + (r & 3) + 8 * (r >> 2) + 4 * lhi;
            const int ks = ksbase + (l31 >> 4);
            const int k16 = l31 & 15;
            Vf[(size_t)(tile * 4 + ks) * 8192 + (k16 >> 3) * 4096 + c * 8 + (k16 & 7)] =
                (_Float16)acc[ct][r];
        }
}

// ---- flash20: flash17 structure (verified no-spill) + validated fixes, with
// register pressure strictly REDUCED:
// (1) V staging via global_load_lds width=16 (wave-uniform LDS base + lane*16,
//     linear copy): removes st0-3 (16 VGPRs) + all stage ds_write VALU.
// (2) Shared-ref fast path WITHOUT PV->QK register coupling: do_qk's reference
//     = max(both streams' mPart of the PREVIOUS slot (LDS), own tilemax). Both
//     streams converge to identical refs -> merge f==1 EXACTLY on max-plateau
//     -> skip sclh8/rescale/exp2. Exact flash algebra (ref >= own running max).
// (3) Vf LDS-matched layout (conflicts 10.5M->2.1M, validated R7).
// (4) QK waves {0,5,10,15} (SIMD-balanced).
__global__ __launch_bounds__(1024, 4) void flash20_kernel(
    const _Float16* __restrict__ Q1, const _Float16* __restrict__ Kf1,
    const _Float16* __restrict__ Q2, const _Float16* __restrict__ Kf2,
    const _Float16* __restrict__ Vf1, const _Float16* __restrict__ Vf2,
    const float* __restrict__ im1, const float* __restrict__ im2,
    float* __restrict__ out)
{
    const int bid = blockIdx.x;
    const int img = bid & 1;
    const int qbase = (bid >> 1) * 64;
    const _Float16* Q = img ? Q1 : Q2;
    const _Float16* Kf = img ? Kf2 : Kf1;
    const _Float16* Vf = img ? Vf2 : Vf1;
    const float* res = img ? im2 : im1;
    float* o = out + (size_t)img * NN * CC;

    __shared__ __align__(16) _Float16 Vs[2][4 * 2 * 512 * 8];  // [buf][(ks*2+h)*4096+c*8+k8] 128 KB
    __shared__ __align__(16) _Float16 P[2][8][64][8];          // [buf][chunk][q][fine] 16 KB
    __shared__ float mPart[2][2][64];                          // [buf][a][q]
    __shared__ float mF[2][64], lF[2][64];

    const int tid = threadIdx.x;
    const int lane = tid & 63, w = tid >> 6;
    const int l31 = lane & 31, lhi = lane >> 5;
    const bool isqk = (w == 0) | (w == 5) | (w == 10) | (w == 15);
    const int qi = w / 5;              // 0..3 for the QK waves
    const int a = qi & 1, b = qi >> 1;

    // ---- PV state: wave owns cols 32w..32w+31 over 64 q (2 q-halves)
    f32x16 acc[2];
#pragma unroll
    for (int t = 0; t < 2; t++)
#pragma unroll
        for (int r = 0; r < 16; r++) acc[t][r] = 0.f;
    float mg_run0 = -3e38f, mg_run1 = -3e38f;  // named scalars, never runtime-indexed

    // ---- QK state (QK waves only): stream = kv-half a, q-half b
    f16x8 qf[4], kreg[4];
    float ma_run = -3e38f, l_run = 0.f;

    const _Float16* kb = Kf + (size_t)(32 * a + l31) * 16 + 8 * lhi;

    if (isqk) {
        const _Float16* qp = Q + (size_t)(qbase + 32 * b + l31) * DKK + 8 * lhi;
#pragma unroll
        for (int k = 0; k < 4; k++) qf[k] = *(const f16x8*)(qp + 16 * k);
#pragma unroll
        for (int k = 0; k < 4; k++) kreg[k] = *(const f16x8*)(kb + (size_t)k * 1024);
    }

    // async V stage: 4x 16B/lane direct global->LDS (no VGPR roundtrip)
    auto stage_async = [&](int t) {
        const _Float16* src = Vf + (size_t)t * 32768 + w * 2048 + lane * 8;
        _Float16* dst = &Vs[t & 1][0] + w * 2048 + lane * 8;
        async_cp16(src, dst);
        async_cp16(src + 512, dst + 512);
        async_cp16(src + 1024, dst + 1024);
        async_cp16(src + 1536, dst + 1536);
    };

    // QK for tile ss: consumes kreg, prefetches kreg(ss+1). Shared ref from the
    // PREVIOUS slot's mPart (both streams, LDS) -> no PV-state coupling.
    auto do_qk = [&](int ss, bool first) {
        const int pbuf = ss & 1;
        f32x16 sA;
#pragma unroll
        for (int r = 0; r < 16; r++) sA[r] = 0.f;
#pragma unroll
        for (int k = 0; k < 4; k++) sA = mfma32(kreg[k], qf[k], sA);
        if (ss + 1 < 128) {
#pragma unroll
            for (int k = 0; k < 4; k++)
                kreg[k] = *(const f16x8*)(kb + (size_t)((ss + 1) * 4 + k) * 1024);
        }
        float mr[8];
#pragma unroll
        for (int i = 0; i < 8; i++) mr[i] = fmaxf(sA[i], sA[i + 8]);
#pragma unroll
        for (int i = 0; i < 4; i++) mr[i] = fmaxf(mr[i], mr[i + 4]);
        float mx = fmaxf(fmaxf(mr[0], mr[1]), fmaxf(mr[2], mr[3]));
        mx = fmaxf(mx, __shfl_xor(mx, 32));
        float ref = mx;
        if (!first) {
            const int rb = (ss + 1) & 1;  // previous slot's buffer
            const float c0 = mPart[rb][0][32 * b + l31];
            const float c1 = mPart[rb][1][32 * b + l31];
            ref = fmaxf(ref, fmaxf(c0, c1));
        }
        const float manew = fmaxf(ma_run, ref);
        if (lane < 32) mPart[pbuf][a][32 * b + lane] = manew;
        float ls = 0.f;
#pragma unroll
        for (int r = 0; r < 16; r++) {
            float p = exp2fast(sA[r] - manew);
            ls += p;
            sA[r] = p;
        }
        ls += __shfl_xor(ls, 32);
        l_run = l_run * exp2fast(ma_run - manew) + ls;
        ma_run = manew;
        // kv_local = (r&3) + 8*(r>>2) + 4*lhi + 32*a -> chunk 4a+(r>>2)
#pragma unroll
        for (int gg = 0; gg < 4; gg++) {
            f16x4 p4;
#pragma unroll
            for (int u = 0; u < 4; u++) p4[u] = (_Float16)sA[gg * 4 + u];
            *(f16x4*)&P[pbuf][4 * a + gg][32 * b + l31][4 * lhi] = p4;
        }
    };

    // ---- prologue: V(0) async-staged; QK(0) with own-ref only
    stage_async(0);
    if (isqk) do_qk(0, true);
    __syncthreads();  // compiler drains vmcnt before barrier -> V(0) landed

    for (int s = 0; s < 128; s++) {
        const int pbuf = s & 1;
        if (s < 127) {
            stage_async(s + 1);                // V(s+1) -> other buffer, async
            if (isqk) do_qk(s + 1, false);     // writes P[(s+1)&1], mPart[(s+1)&1]
        }

        // ---- merge (shared-ref fast path: skip all exp2/rescale on plateau)
        float lal0, lal1, lf00, lf01, lf10, lf11;
        bool fastall;
        {
            const float m00 = mPart[pbuf][0][l31];
            const float m10 = mPart[pbuf][1][l31];
            const float mgn0 = fmaxf(mg_run0, fmaxf(m00, m10));
            const float m01 = mPart[pbuf][0][32 + l31];
            const float m11 = mPart[pbuf][1][32 + l31];
            const float mgn1 = fmaxf(mg_run1, fmaxf(m01, m11));
            fastall = (m00 == mgn0) & (m10 == mgn0) & (mg_run0 == mgn0) &
                      (m01 == mgn1) & (m11 == mgn1) & (mg_run1 == mgn1);
            lal0 = mg_run0 - mgn0;  lal1 = mg_run1 - mgn1;
            lf00 = m00 - mgn0;      lf01 = m01 - mgn1;
            lf10 = m10 - mgn0;      lf11 = m11 - mgn1;
            mg_run0 = mgn0;         mg_run1 = mgn1;
        }
        const bool nos = __all(fastall);
        const _Float16* vbufp = &Vs[pbuf][0];

        if (nos) {
#pragma unroll
            for (int ks = 0; ks < 4; ks++) {
                f16x8 va = *(const f16x8*)(vbufp + (ks * 2 + lhi) * 4096 + (32 * w + l31) * 8);
                f16x8 pb0 = *(const f16x8*)&P[pbuf][2 * ks + lhi][l31][0];
                f16x8 pb1 = *(const f16x8*)&P[pbuf][2 * ks + lhi][32 + l31][0];
                acc[0] = mfma32(va, pb0, acc[0]);
                acc[1] = mfma32(va, pb1, acc[1]);
            }
        } else {
            const float al0 = exp2fast(lal0), al1 = exp2fast(lal1);
            const float f00 = exp2fast(lf00), f01 = exp2fast(lf01);
            const float f10 = exp2fast(lf10), f11 = exp2fast(lf11);
#pragma unroll
            for (int r = 0; r < 16; r++) { acc[0][r] *= al0; acc[1][r] *= al1; }
#pragma unroll
            for (int ks = 0; ks < 4; ks++) {
                f16x8 va = *(const f16x8*)(vbufp + (ks * 2 + lhi) * 4096 + (32 * w + l31) * 8);
                f16x8 pb0 = *(const f16x8*)&P[pbuf][2 * ks + lhi][l31][0];
                f16x8 pb1 = *(const f16x8*)&P[pbuf][2 * ks + lhi][32 + l31][0];
                pb0 = sclh8(pb0, (_Float16)(ks < 2 ? f00 : f10));
                pb1 = sclh8(pb1, (_Float16)(ks < 2 ? f01 : f11));
                acc[0] = mfma32(va, pb0, acc[0]);
                acc[1] = mfma32(va, pb1, acc[1]);
            }
        }

        __syncthreads();  // vmcnt drained: V(s+1) landed; P(s+1) written; slot-s reads done
    }

    // ---- epilogue: 2-stream denominator; direct store with residual
    if (isqk && lane < 32) {
        mF[a][32 * b + lane] = ma_run;
        lF[a][32 * b + lane] = l_run;
    }
    __syncthreads();

    float fac0, fac1;
    {
        const float M0 = mg_run0;  // final merged max (>= both stream refs)
        fac0 = 1.f / (lF[0][l31] * exp2fast(mF[0][l31] - M0) +
                      lF[1][l31] * exp2fast(mF[1][l31] - M0));
        const float M1 = mg_run1;
        fac1 = 1.f / (lF[0][32 + l31] * exp2fast(mF[0][32 + l31] - M1) +
                      lF[1][32 + l31] * exp2fast(mF[1][32 + l31] - M1));
    }

#pragma unroll
    for (int rg = 0; rg < 4; rg++) {
        const int c = 32 * w + 8 * rg + 4 * lhi;
        const size_t off0 = (size_t)(qbase + l31) * CC + c;
        const size_t off1 = (size_t)(qbase + 32 + l31) * CC + c;
        f32x4 v0, v1;
#pragma unroll
        for (int u = 0; u < 4; u++) { v0[u] = acc[0][4 * rg + u] * fac0; v1[u] = acc[1][4 * rg + u] * fac1; }
        f32x4 r0 = *(const f32x4*)(res + off0);
        f32x4 r1 = *(const f32x4*)(res + off1);
        *(f32x4*)(o + off0) = v0 + r0;
        *(f32x4*)(o + off1) = v1 + r1;
    }
}

extern "C" void kernel_launch(void* const* d_in, const int* in_sizes, int n_in,
                              void* d_out, int out_size, void* d_ws, size_t ws_size,
                              hipStream_t stream) {
    const float* im1 = (const float*)d_in[0];
    const float* im2 = (const float*)d_in[1];
    const float* Wq  = (const float*)d_in[2];
    const float* Wk  = (const float*)d_in[3];
    const float* Wv  = (const float*)d_in[4];
    float* out = (float*)d_out;

    _Float16* w = (_Float16*)d_ws;
    _Float16* Wqt = w;                      // 64*512
    _Float16* Wkt = Wqt + 64 * 512;
    _Float16* Wvf = Wkt + 64 * 512;         // 512*512 frag-major
    _Float16* Q1  = Wvf + 512 * 512;        // 8192*64 each
    _Float16* Kf1 = Q1 + NN * DKK;
    _Float16* Q2  = Kf1 + NN * DKK;
    _Float16* Kf2 = Q2 + NN * DKK;
    _Float16* Vf1 = Kf2 + NN * DKK;         // LDS-matched [128][4][2][512][8] each
    _Float16* Vf2 = Vf1 + (size_t)CC * NN;

    wtrans_all_kernel<<<1280, 256, 0, stream>>>(Wq, Wk, Wv, Wqt, Wkt, Wvf);
    proj_qk2_kernel<<<dim3(128, 2), 256, 0, stream>>>(im1, im2, Wqt, Wkt, Q1, Kf1, Q2, Kf2);
    proj_vt_kernel<<<dim3(256, 2), 256, 0, stream>>>(im1, im2, Wvf, Vf1, Vf2);
    flash20_kernel<<<256, 1024, 0, stream>>>(Q1, Kf1, Q2, Kf2, Vf1, Vf2, im1, im2, out);
}

// Round 10
// 396.954 us; speedup vs baseline: 3.3862x; 1.5777x over previous
//
#include <hip/hip_runtime.h>

#define NN 8192
#define CC 512
#define DKK 64

typedef float f32x4 __attribute__((ext_vector_type(4)));
typedef float f32x16 __attribute__((ext_vector_type(16)));
typedef _Float16 f16x8 __attribute__((ext_vector_type(8)));
typedef _Float16 f16x4 __attribute__((ext_vector_type(4)));

__device__ __forceinline__ f32x4 mfma16(f16x8 a, f16x8 b, f32x4 c) {
    return __builtin_amdgcn_mfma_f32_16x16x32_f16(a, b, c, 0, 0, 0);
}
__device__ __forceinline__ f32x16 mfma32(f16x8 a, f16x8 b, f32x16 c) {
    return __builtin_amdgcn_mfma_f32_32x32x16_f16(a, b, c, 0, 0, 0);
}
__device__ __forceinline__ f16x8 scl8(f16x8 v, float f) {
    _Float16 h = (_Float16)f;
    f16x8 r;
#pragma unroll
    for (int i = 0; i < 8; i++) r[i] = v[i] * h;
    return r;
}
__device__ __forceinline__ float exp2fast(float x) { return __builtin_exp2f(x); }

// ---- all weight transposes in one launch. grid 1280 x 256.
// Wqt: 64*512; Wkt: 64*512; Wvf: 512*512 frag-major [ks][c][k16].
__global__ void wtrans_all_kernel(const float* __restrict__ Wq, const float* __restrict__ Wk,
                                  const float* __restrict__ Wv,
                                  _Float16* __restrict__ Wqt, _Float16* __restrict__ Wkt,
                                  _Float16* __restrict__ Wvf) {
    int idx = blockIdx.x * 256 + threadIdx.x;
    if (idx < 32768) {
        int n = idx >> 9, k = idx & 511;
        Wqt[idx] = (_Float16)Wq[k * 64 + n];
    } else if (idx < 65536) {
        int j = idx - 32768;
        int n = j >> 9, k = j & 511;
        Wkt[j] = (_Float16)Wk[k * 64 + n];
    } else {
        int j = idx - 65536;
        int k16 = j & 15, c = (j >> 4) & 511, ks = j >> 13;
        Wvf[j] = (_Float16)Wv[(size_t)(16 * ks + k16) * 512 + c];
    }
}

// ---- fused Q+K projection, 512 thr / 128 rows per block, grid (64,2).
// Q[N][64] row-major f16, PRE-SCALED by log2(e) (flash softmax in exp2 domain);
// K -> frag-major Kf[tile=n>>6][ks=dk>>4][kv6=n&63][k16=dk&15].
__global__ __launch_bounds__(512) void proj_qk2_kernel(
    const float* __restrict__ im1, const float* __restrict__ im2,
    const _Float16* __restrict__ Wqt, const _Float16* __restrict__ Wkt,
    _Float16* __restrict__ Q1, _Float16* __restrict__ Kf1,
    _Float16* __restrict__ Q2, _Float16* __restrict__ Kf2)
{
    const float* X = blockIdx.y ? im2 : im1;
    _Float16* Q = blockIdx.y ? Q2 : Q1;
    _Float16* Kf = blockIdx.y ? Kf2 : Kf1;

    __shared__ __align__(16) _Float16 Wlds[128 * 512];  // 128 KB

    const int tid = threadIdx.x;
    const int lane = tid & 63, wave = tid >> 6;
    const int n16 = lane & 15, quad = lane >> 4;

#pragma unroll
    for (int i = 0; i < 16; i++) {
        const int idx = tid + 512 * i;
        const int row = idx >> 6, ch = idx & 63;
        const _Float16* src = (row < 64) ? (Wqt + (size_t)row * 512 + ch * 8)
                                         : (Wkt + (size_t)(row - 64) * 512 + ch * 8);
        *(f16x8*)&Wlds[row * 512 + ((ch ^ (row & 7)) * 8)] = *(const f16x8*)src;
    }
    __syncthreads();

    const int arow = blockIdx.x * 128 + wave * 16 + n16;
    f32x4 acc[8];
#pragma unroll
    for (int i = 0; i < 8; i++) acc[i] = (f32x4){0.f, 0.f, 0.f, 0.f};

    const float* xbase = X + (size_t)arow * 512 + quad * 8;
    for (int kk = 0; kk < 16; kk++) {
        f32x4 xa = *(const f32x4*)(xbase + kk * 32);
        f32x4 xb = *(const f32x4*)(xbase + kk * 32 + 4);
        f16x8 afrag;
#pragma unroll
        for (int j = 0; j < 4; j++) { afrag[j] = (_Float16)xa[j]; afrag[4 + j] = (_Float16)xb[j]; }
#pragma unroll
        for (int t = 0; t < 8; t++) {
            const int row = t * 16 + n16;
            f16x8 bfr = *(const f16x8*)&Wlds[row * 512 + (((4 * kk + quad) ^ (row & 7)) * 8)];
            acc[t] = mfma16(afrag, bfr, acc[t]);
        }
    }
    const int lr0 = wave * 16 + quad * 4;
    const int rbase = blockIdx.x * 128 + lr0;
#pragma unroll
    for (int t = 0; t < 4; t++)
#pragma unroll
        for (int r = 0; r < 4; r++) {
            Q[(size_t)(rbase + r) * 64 + t * 16 + n16] = (_Float16)(acc[t][r] * 1.44269504f);
            const int lrr = lr0 + r;  // 0..127
            Kf[((size_t)(blockIdx.x * 8 + (lrr >> 6) * 4 + t) * 64 + (lrr & 63)) * 16 + n16] =
                (_Float16)acc[4 + t][r];
        }
}

// ---- V projection -> frag-major Vf[tile][ks][c=512][n16] (flash6 layout).
// 512 thr / 64 rows per block, grid (128,2): halves Wvf re-reads, doubles waves.
__global__ __launch_bounds__(512) void proj_vt_kernel(
    const float* __restrict__ im1, const float* __restrict__ im2,
    const _Float16* __restrict__ Wvf,
    _Float16* __restrict__ Vf1, _Float16* __restrict__ Vf2)
{
    const float* X = blockIdx.y ? im2 : im1;
    _Float16* Vf = blockIdx.y ? Vf2 : Vf1;
    const int n0 = blockIdx.x * 64;
    const int tid = threadIdx.x;
    const int lane = tid & 63, wave = tid >> 6;
    const int l31 = lane & 31, lhi = lane >> 5;
    const int rowgrp = wave >> 2, w4 = wave & 3;

    __shared__ __align__(16) _Float16 Xlds[64 * 512];  // 64 KB

#pragma unroll
    for (int i = 0; i < 8; i++) {
        const int n = tid >> 3;               // 0..63
        const int chunk = (tid & 7) + 8 * i;  // 0..63
        const float* xp = X + (size_t)(n0 + n) * CC + chunk * 8;
        f32x4 x0 = *(const f32x4*)xp;
        f32x4 x1 = *(const f32x4*)(xp + 4);
        f16x8 d;
#pragma unroll
        for (int j = 0; j < 4; j++) { d[j] = (_Float16)x0[j]; d[4 + j] = (_Float16)x1[j]; }
        *(f16x8*)&Xlds[n * 512 + ((chunk ^ (n & 7)) * 8)] = d;
    }
    __syncthreads();

    f32x16 acc[4];
#pragma unroll
    for (int t = 0; t < 4; t++)
#pragma unroll
        for (int r = 0; r < 16; r++) acc[t][r] = 0.f;

    const int xrow = rowgrp * 32 + l31;
    for (int ks = 0; ks < 32; ks++) {
        f16x8 xb = *(const f16x8*)&Xlds[xrow * 512 + (((2 * ks + lhi) ^ (xrow & 7)) * 8)];
#pragma unroll
        for (int ct = 0; ct < 4; ct++) {
            const _Float16* wp = Wvf + ((size_t)ks * 512 + 128 * w4 + 32 * ct + l31) * 16 + 8 * lhi;
            acc[ct] = mfma32(*(const f16x8*)wp, xb, acc[ct]);
        }
    }
    const int tile = blockIdx.x;
#pragma unroll
    for (int ct = 0; ct < 4; ct++)
#pragma unroll
        for (int r = 0; r < 16; r++) {
            const int c = 128 * w4 + 32 * ct + (r & 3) + 8 * (r >> 2) + 4 * lhi;
            const int ks = rowgrp * 2 + (l31 >> 4);
            Vf[((size_t)(tile * 4 + ks) * 512 + c) * 16 + (l31 & 15)] = (_Float16)acc[ct][r];
        }
}

// ---- flash6 (measured best: 235 us) restored verbatim from R1, with the single
// validated change: exp2-domain softmax (__expf -> v_exp_f32; Q pre-scaled).
__global__ __launch_bounds__(512, 4) void flash6_kernel(
    const _Float16* __restrict__ Q1, const _Float16* __restrict__ Kf1,
    const _Float16* __restrict__ Q2, const _Float16* __restrict__ Kf2,
    const _Float16* __restrict__ Vf1, const _Float16* __restrict__ Vf2,
    const float* __restrict__ im1, const float* __restrict__ im2,
    float* __restrict__ out)
{
    const int img = blockIdx.y;
    const _Float16* Q = img ? Q1 : Q2;
    const _Float16* Kf = img ? Kf2 : Kf1;
    const _Float16* Vf = img ? Vf2 : Vf1;
    const float* res = img ? im2 : im1;
    float* o = out + (size_t)img * NN * CC;

    __shared__ __align__(16) _Float16 P[2][4][8][32][8];
    __shared__ float mPart[2][4][2][32];
    __shared__ float mF[4][2][32], lF[4][2][32];

    const int tid = threadIdx.x;
    const int lane = tid & 63, w = tid >> 6;
    const int l31 = lane & 31, lhi = lane >> 5;
    const int g = w >> 1, a = w & 1;
    const int qbase = blockIdx.x * 32;

    f16x8 qf[4];
    {
        const _Float16* qp = Q + (size_t)(qbase + l31) * DKK + 8 * lhi;
#pragma unroll
        for (int k = 0; k < 4; k++) qf[k] = *(const f16x8*)(qp + 16 * k);
    }

    f32x16 acc[2];
#pragma unroll
    for (int t = 0; t < 2; t++)
#pragma unroll
        for (int r = 0; r < 16; r++) acc[t][r] = 0.f;

    float ma_run = -3e38f, l_run = 0.f;
    float mg_run = -3e38f;

    const _Float16* kb = Kf + ((size_t)(32 * a + l31)) * 16 + 8 * lhi;
    const _Float16* vb = Vf + ((size_t)(64 * w + l31)) * 16 + 8 * lhi;

    auto do_qk = [&](int s) {
        const int t = 4 * s + g;
        const int pbuf = s & 1;
        f32x16 sA;
#pragma unroll
        for (int r = 0; r < 16; r++) sA[r] = 0.f;
#pragma unroll
        for (int k = 0; k < 4; k++) {
            f16x8 kf = *(const f16x8*)(kb + (size_t)(t * 4 + k) * (64 * 16));
            sA = mfma32(kf, qf[k], sA);
        }
        float mr[8];
#pragma unroll
        for (int i = 0; i < 8; i++) mr[i] = fmaxf(sA[i], sA[i + 8]);
#pragma unroll
        for (int i = 0; i < 4; i++) mr[i] = fmaxf(mr[i], mr[i + 4]);
        float mx = fmaxf(fmaxf(mr[0], mr[1]), fmaxf(mr[2], mr[3]));
        mx = fmaxf(mx, __shfl_xor(mx, 32));
        const float manew = fmaxf(ma_run, mx);
        if (lane < 32) mPart[pbuf][g][a][lane] = manew;
        float ls = 0.f;
#pragma unroll
        for (int r = 0; r < 16; r++) {
            float p = exp2fast(sA[r] - manew);
            ls += p;
            sA[r] = p;
        }
        ls += __shfl_xor(ls, 32);
        l_run = l_run * exp2fast(ma_run - manew) + ls;
        ma_run = manew;
#pragma unroll
        for (int gg = 0; gg < 4; gg++) {
            f16x4 p4;
#pragma unroll
            for (int u = 0; u < 4; u++) p4[u] = (_Float16)sA[gg * 4 + u];
            *(f16x4*)&P[pbuf][g][4 * a + gg][l31][4 * lhi] = p4;
        }
    };

    do_qk(0);
    __syncthreads();

    for (int s = 0; s < 32; s++) {
        const int pbuf = s & 1;

        // early V-frag issue for PV(s) k=0, all 4 tiles (hides L2 latency)
        f16x8 va0[4];
#pragma unroll
        for (int tt = 0; tt < 4; tt++)
            va0[tt] = *(const f16x8*)(vb + ((size_t)((4 * s + tt) * 4) * 512) * 16);

        if (s < 31) do_qk(s + 1);

        float f[4][2];
        float mgn = mg_run;
#pragma unroll
        for (int g2 = 0; g2 < 4; g2++)
#pragma unroll
            for (int a2 = 0; a2 < 2; a2++) {
                f[g2][a2] = mPart[pbuf][g2][a2][l31];
                mgn = fmaxf(mgn, f[g2][a2]);
            }
        const float al = exp2fast(mg_run - mgn);
        mg_run = mgn;
        if (!__all(al == 1.f)) {
#pragma unroll
            for (int t2 = 0; t2 < 2; t2++)
#pragma unroll
                for (int r = 0; r < 16; r++) acc[t2][r] *= al;
        }
        bool nos1 = true;
#pragma unroll
        for (int g2 = 0; g2 < 4; g2++)
#pragma unroll
            for (int a2 = 0; a2 < 2; a2++) {
                f[g2][a2] = exp2fast(f[g2][a2] - mgn);
                nos1 &= (f[g2][a2] == 1.f);
            }
        const bool nos = __all(nos1);

#pragma unroll
        for (int tt = 0; tt < 4; tt++)
#pragma unroll
            for (int k = 0; k < 4; k++) {
                f16x8 pb = *(const f16x8*)&P[pbuf][tt][2 * k + lhi][l31][0];
                if (!nos) pb = scl8(pb, f[tt][k >> 1]);
                f16x8 va = (k == 0) ? va0[tt]
                    : *(const f16x8*)(vb + (size_t)(((4 * s + tt) * 4 + k) * 512) * 16);
                acc[0] = mfma32(va, pb, acc[0]);
                // second q... (flash6 owns 32 cols per wave pair? no: 2 accs = 2 col-tiles)
                f16x8 va2 = va;  // same V frag feeds both col-tiles? no-op guard
                (void)va2;
                acc[1] = mfma32(*(const f16x8*)(vb +
                    (size_t)(((4 * s + tt) * 4 + k) * 512 + 32) * 16), pb, acc[1]);
            }
        __syncthreads();
    }

    if (lane < 32) {
        mF[g][a][lane] = ma_run;
        lF[g][a][lane] = l_run;
    }
    __syncthreads();

    const float M = mg_run;
    float den = 0.f;
#pragma unroll
    for (int g2 = 0; g2 < 4; g2++)
#pragma unroll
        for (int a2 = 0; a2 < 2; a2++)
            den += lF[g2][a2][l31] * exp2fast(mF[g2][a2][l31] - M);
    const float fac = 1.f / den;

#pragma unroll
    for (int ct = 0; ct < 2; ct++)
#pragma unroll
        for (int rg = 0; rg < 4; rg++) {
            const int c = 64 * w + 32 * ct + 8 * rg + 4 * lhi;
            const size_t off = (size_t)(qbase + l31) * CC + c;
            f32x4 v;
#pragma unroll
            for (int u = 0; u < 4; u++) v[u] = acc[ct][4 * rg + u] * fac;
            f32x4 r4 = *(const f32x4*)(res + off);
            *(f32x4*)(o + off) = v + r4;
        }
}

extern "C" void kernel_launch(void* const* d_in, const int* in_sizes, int n_in,
                              void* d_out, int out_size, void* d_ws, size_t ws_size,
                              hipStream_t stream) {
    const float* im1 = (const float*)d_in[0];
    const float* im2 = (const float*)d_in[1];
    const float* Wq  = (const float*)d_in[2];
    const float* Wk  = (const float*)d_in[3];
    const float* Wv  = (const float*)d_in[4];
    float* out = (float*)d_out;

    _Float16* w = (_Float16*)d_ws;
    _Float16* Wqt = w;                      // 64*512
    _Float16* Wkt = Wqt + 64 * 512;
    _Float16* Wvf = Wkt + 64 * 512;         // 512*512 frag-major
    _Float16* Q1  = Wvf + 512 * 512;        // 8192*64 each
    _Float16* Kf1 = Q1 + NN * DKK;
    _Float16* Q2  = Kf1 + NN * DKK;
    _Float16* Kf2 = Q2 + NN * DKK;
    _Float16* Vf1 = Kf2 + NN * DKK;         // frag-major [128][4][512][16] each
    _Float16* Vf2 = Vf1 + (size_t)CC * NN;

    wtrans_all_kernel<<<1280, 256, 0, stream>>>(Wq, Wk, Wv, Wqt, Wkt, Wvf);
    proj_qk2_kernel<<<dim3(64, 2), 512, 0, stream>>>(im1, im2, Wqt, Wkt, Q1, Kf1, Q2, Kf2);
    proj_vt_kernel<<<dim3(128, 2), 512, 0, stream>>>(im1, im2, Wvf, Vf1, Vf2);
    flash6_kernel<<<dim3(256, 2), 512, 0, stream>>>(Q1, Kf1, Q2, Kf2, Vf1, Vf2, im1, im2, out);
}